// Round 9
// baseline (219.804 us; speedup 1.0000x reference)
//
#include <hip/hip_runtime.h>
#include <math.h>

#define T_DIM 2048
#define B_DIM 2
#define C_DIM 1024
#define H_DIM 16
#define D_DIM 64
#define M_DIM (T_DIM * B_DIM)   // 4096
#define SCALE_Q 0.125f          // D^-0.5

typedef short short8 __attribute__((ext_vector_type(8)));
typedef float f32x4  __attribute__((ext_vector_type(4)));
typedef unsigned short ushort_t;

__device__ __forceinline__ unsigned short f2bf(float f) {
    unsigned int u = __builtin_bit_cast(unsigned int, f);
    u += 0x7FFFu + ((u >> 16) & 1u);           // round-to-nearest-even
    return (unsigned short)(u >> 16);
}

__device__ __forceinline__ void gl_lds16(const void* g, void* l) {
    __builtin_amdgcn_global_load_lds(
        (const __attribute__((address_space(1))) void*)g,
        (__attribute__((address_space(3))) void*)l, 16, 0, 0);
}

// ---------------------------------------------------------------------------
// prep: fused input conversion.
//   z<4 : transpose-cast w (k,n) fp32 -> w^T (n,k) bf16 (64x64 LDS tiles)
//   z==4: straight cast x fp32 -> bf16
// ---------------------------------------------------------------------------
__global__ __launch_bounds__(256) void prep(
    const float* __restrict__ x,
    const float* __restrict__ wq, const float* __restrict__ wk,
    const float* __restrict__ wv, const float* __restrict__ wo,
    ushort_t* __restrict__ xb,
    ushort_t* __restrict__ wqkv_t, ushort_t* __restrict__ wo_t)
{
    __shared__ float tile[64][65];
    const int tid = threadIdx.x;
    const int z   = blockIdx.z;

    if (z == 4) {   // cast x
        const size_t base =
            ((size_t)(blockIdx.y * 16 + blockIdx.x)) * 16384 + (size_t)tid * 8;
#pragma unroll
        for (int j = 0; j < 8; ++j) {
            const size_t i = base + (size_t)j * 2048;
            const float4 v0 = *(const float4*)&x[i];
            const float4 v1 = *(const float4*)&x[i + 4];
            ushort_t o[8] = {f2bf(v0.x), f2bf(v0.y), f2bf(v0.z), f2bf(v0.w),
                             f2bf(v1.x), f2bf(v1.y), f2bf(v1.z), f2bf(v1.w)};
            *(uint4*)&xb[i] = *(uint4*)o;
        }
        return;
    }

    const int k0 = blockIdx.x * 64;
    const int n0 = blockIdx.y * 64;
    const float* src = (z == 0) ? wq : (z == 1) ? wk : (z == 2) ? wv : wo;
    ushort_t* dst = (z < 3) ? (wqkv_t + (size_t)z * C_DIM * C_DIM) : wo_t;

    const int r = tid >> 4;
    const int c = (tid & 15) * 4;
#pragma unroll
    for (int i = 0; i < 4; ++i) {
        const float4 v = *(const float4*)&src[(size_t)(k0 + r + i * 16) * C_DIM + n0 + c];
        *(float4*)&tile[r + i * 16][c] = v;
    }
    __syncthreads();
#pragma unroll
    for (int i = 0; i < 4; ++i) {
        const int r2 = r + i * 16;        // n-rel
        ushort4 o;
        o.x = f2bf(tile[c + 0][r2]); o.y = f2bf(tile[c + 1][r2]);
        o.z = f2bf(tile[c + 2][r2]); o.w = f2bf(tile[c + 3][r2]);
        *(ushort4*)&dst[(size_t)(n0 + r2) * C_DIM + k0 + c] = o;
    }
}

// ---------------------------------------------------------------------------
// QKV projection, bf16 MFMA. 128x128 tile, BK=64 (16 barriers instead of 32),
// 4 waves. Epilogue: per-wave LDS transpose -> coalesced stores. q/k natural
// (bh,t,d) (q scaled); v written TRANSPOSED (bh,d,t) via LDS column gather
// (fuses the old v_transpose kernel).
// LDS: max(As+Bs = 32 KB, Ep = 4 x 64x72 = 36 KB) = 36.9 KB -> 4 blocks/CU.
// ---------------------------------------------------------------------------
__global__ __launch_bounds__(256) void qkv_mfma(
    const ushort_t* __restrict__ xb, const ushort_t* __restrict__ wt,
    ushort_t* __restrict__ q_ws, ushort_t* __restrict__ k_ws,
    ushort_t* __restrict__ v_t)
{
    __shared__ ushort_t lds[18432];      // 36,864 B
    ushort_t* As = lds;                  // [128*64]
    ushort_t* Bs = lds + 8192;           // [128*64]

    const int tid  = threadIdx.x;
    const int n0   = blockIdx.x * 128;   // 0..2944
    const int m0   = blockIdx.y * 128;
    const int w    = tid >> 6;
    const int lane = tid & 63;
    const int l16  = lane & 15;
    const int quad = lane >> 4;
    const int wm   = (w >> 1) * 64;
    const int wn   = (w & 1) * 64;

    // staging: 4 16B chunks each for A and B per BK=64 iter.
    // chunk ci = tid + j*256: row = ci>>3, col8 = (tid&7)*8 (j-invariant)
    const int srow = tid >> 3;
    const int sc8  = (tid & 7) * 8;
    const ushort_t* aP[4];
    const ushort_t* bP[4];
#pragma unroll
    for (int j = 0; j < 4; ++j) {
        aP[j] = xb + (size_t)(m0 + srow + j * 32) * C_DIM + sc8;
        bP[j] = wt + (size_t)(n0 + srow + j * 32) * C_DIM + sc8;
    }
    const int ldso = tid * 8;            // + j*2048

    f32x4 acc[4][4] = {};

    for (int k0 = 0; k0 < C_DIM; k0 += 64) {
        __syncthreads();
#pragma unroll
        for (int j = 0; j < 4; ++j) {
            gl_lds16(aP[j] + k0, As + ldso + j * 2048);
            gl_lds16(bP[j] + k0, Bs + ldso + j * 2048);
        }
        __syncthreads();

#pragma unroll
        for (int s = 0; s < 2; ++s) {
            short8 af[4], bf[4];
#pragma unroll
            for (int mi = 0; mi < 4; ++mi)
                af[mi] = *(const short8*)&As[(wm + mi * 16 + l16) * 64 + s * 32 + quad * 8];
#pragma unroll
            for (int ni = 0; ni < 4; ++ni)
                bf[ni] = *(const short8*)&Bs[(wn + ni * 16 + l16) * 64 + s * 32 + quad * 8];
#pragma unroll
            for (int mi = 0; mi < 4; ++mi)
#pragma unroll
                for (int ni = 0; ni < 4; ++ni)
                    acc[mi][ni] = __builtin_amdgcn_mfma_f32_16x16x32_bf16(
                        af[mi], bf[ni], acc[mi][ni], 0, 0, 0);
        }
    }

    // ---- epilogue: wave-private LDS transpose, then coalesced stores ----
    __syncthreads();
    ushort_t* Ep = lds + w * 4608;         // 64 rows x 72 pitch

    const int mat = n0 >> 10;              // 0=q 1=k 2=v
    const int cb  = (n0 & 1023) + wn;      // head-aligned quadrant
    const int h   = cb >> 6;
    const float sc = (mat == 0) ? SCALE_Q : 1.0f;

#pragma unroll
    for (int mi = 0; mi < 4; ++mi)
#pragma unroll
        for (int ni = 0; ni < 4; ++ni)
#pragma unroll
            for (int r = 0; r < 4; ++r)
                Ep[(mi * 16 + quad * 4 + r) * 72 + ni * 16 + l16] =
                    f2bf(acc[mi][ni][r] * sc);
    // wave-private region: lgkmcnt dependency only

    if (mat == 2) {
        // v^T store: (bh, d, t). lane = (dq, b, tc); d = p*8+dq, t chunk tc.
        const int dq  = lane >> 3;         // 0..7
        const int b   = (lane >> 2) & 1;
        const int tc  = lane & 3;          // 0..3 (8 t each)
        const int tg0 = (m0 + wm) >> 1;    // global t base (m0+wm even)
#pragma unroll
        for (int p = 0; p < 8; ++p) {
            const int d = p * 8 + dq;
            ushort_t o[8];
#pragma unroll
            for (int i = 0; i < 8; ++i)
                o[i] = Ep[(2 * (tc * 8 + i) + b) * 72 + d];
            *(uint4*)&v_t[((size_t)(b * H_DIM + h) * D_DIM + d) * T_DIM + tg0 + tc * 8] =
                *(uint4*)o;
        }
    } else {
        ushort_t* dst = (mat == 0) ? q_ws : k_ws;
        const int rq = lane >> 3;
        const int c8 = (lane & 7) * 8;
#pragma unroll
        for (int p = 0; p < 8; ++p) {
            const int row = p * 8 + rq;
            const uint4 val = *(const uint4*)&Ep[row * 72 + c8];
            const int m = m0 + wm + row;
            const int t = m >> 1, b = m & 1;
            *(uint4*)&dst[((size_t)(b * H_DIM + h) * T_DIM + t) * D_DIM + c8] = val;
        }
    }
}

// ---------------------------------------------------------------------------
// MFMA flash attention, max-free softmax (unchanged from round 8).
// ---------------------------------------------------------------------------
__global__ __launch_bounds__(256) void attn_mfma(
    const ushort_t* __restrict__ q, const ushort_t* __restrict__ k,
    const ushort_t* __restrict__ v, ushort_t* __restrict__ ctx)
{
    __shared__ ushort_t Ks [64][72];
    __shared__ ushort_t Vts[64][72];
    __shared__ ushort_t Ps [64][72];

    const int tid  = threadIdx.x;
    const int bh   = blockIdx.x;
    const int q0   = blockIdx.y * 64;
    const int w    = tid >> 6;
    const int lane = tid & 63;
    const int l16  = lane & 15;
    const int quad = lane >> 4;

    const int r0 = tid >> 3,         c80 = (tid & 7) * 8;
    const int r1 = (tid + 256) >> 3;
    const ushort_t* kbase = k + (size_t)bh * T_DIM * D_DIM;
    const ushort_t* vbase = v + (size_t)bh * D_DIM * T_DIM;

    short8 aq0, aq1;
    {
        const ushort_t* qrow = q + ((size_t)bh * T_DIM + q0 + 16 * w + l16) * D_DIM;
        aq0 = *(const short8*)(qrow + quad * 8);
        aq1 = *(const short8*)(qrow + 32 + quad * 8);
    }

    short8 vones;
#pragma unroll
    for (int j = 0; j < 8; ++j) vones[j] = (short)0x3F80;

    f32x4 O[4] = {};
    f32x4 Osum = {};

    const ushort_t* kp0 = kbase + (size_t)r0 * D_DIM + c80;
    const ushort_t* kp1 = kbase + (size_t)r1 * D_DIM + c80;
    const ushort_t* vp0 = vbase + (size_t)r0 * T_DIM + c80;
    const ushort_t* vp1 = vbase + (size_t)r1 * T_DIM + c80;
    uint4 kr0 = *(const uint4*)kp0;  kp0 += 64 * D_DIM;
    uint4 kr1 = *(const uint4*)kp1;  kp1 += 64 * D_DIM;
    uint4 vr0 = *(const uint4*)vp0;  vp0 += 64;
    uint4 vr1 = *(const uint4*)vp1;  vp1 += 64;

    const float LOG2E = 1.44269504f;
    const float SHIFT = 8.0f * 1.44269504f;

    for (int kt = 0; kt < 32; ++kt) {
        __syncthreads();
        *(uint4*)&Ks[r0][c80]  = kr0;
        *(uint4*)&Ks[r1][c80]  = kr1;
        *(uint4*)&Vts[r0][c80] = vr0;
        *(uint4*)&Vts[r1][c80] = vr1;
        if (kt + 1 < 32) {
            kr0 = *(const uint4*)kp0;  kp0 += 64 * D_DIM;
            kr1 = *(const uint4*)kp1;  kp1 += 64 * D_DIM;
            vr0 = *(const uint4*)vp0;  vp0 += 64;
            vr1 = *(const uint4*)vp1;  vp1 += 64;
        }
        __syncthreads();

        f32x4 S[4];
#pragma unroll
        for (int nt = 0; nt < 4; ++nt) {
            const short8 b0 = *(const short8*)&Ks[nt * 16 + l16][quad * 8];
            const short8 b1 = *(const short8*)&Ks[nt * 16 + l16][32 + quad * 8];
            f32x4 s = (f32x4){0.f, 0.f, 0.f, 0.f};
            s = __builtin_amdgcn_mfma_f32_16x16x32_bf16(aq0, b0, s, 0, 0, 0);
            s = __builtin_amdgcn_mfma_f32_16x16x32_bf16(aq1, b1, s, 0, 0, 0);
            S[nt] = s;
        }

#pragma unroll
        for (int nt = 0; nt < 4; ++nt)
#pragma unroll
            for (int r = 0; r < 4; ++r) {
                union { float f; ushort2 h; } cv;
                cv.f = exp2f(fmaf(S[nt][r], LOG2E, -SHIFT));
                Ps[16 * w + quad * 4 + r][nt * 16 + l16] = cv.h.y;
            }

        const short8 ap0 = *(const short8*)&Ps[16 * w + l16][quad * 8];
        const short8 ap1 = *(const short8*)&Ps[16 * w + l16][32 + quad * 8];

        Osum = __builtin_amdgcn_mfma_f32_16x16x32_bf16(ap0, vones, Osum, 0, 0, 0);
        Osum = __builtin_amdgcn_mfma_f32_16x16x32_bf16(ap1, vones, Osum, 0, 0, 0);

#pragma unroll
        for (int nt = 0; nt < 4; ++nt) {
            const short8 b0 = *(const short8*)&Vts[nt * 16 + l16][quad * 8];
            const short8 b1 = *(const short8*)&Vts[nt * 16 + l16][32 + quad * 8];
            O[nt] = __builtin_amdgcn_mfma_f32_16x16x32_bf16(ap0, b0, O[nt], 0, 0, 0);
            O[nt] = __builtin_amdgcn_mfma_f32_16x16x32_bf16(ap1, b1, O[nt], 0, 0, 0);
        }
    }

    const int b = bh >> 4;
    const int h = bh & 15;
#pragma unroll
    for (int r = 0; r < 4; ++r) {
        const float inv = 1.0f / Osum[r];
        const int row = q0 + 16 * w + quad * 4 + r;
#pragma unroll
        for (int nt = 0; nt < 4; ++nt)
            ctx[((size_t)row * B_DIM + b) * C_DIM + h * 64 + nt * 16 + l16] =
                f2bf(O[nt][r] * inv);
    }
}

// ---------------------------------------------------------------------------
// Output projection, bf16 MFMA, BK=64: out[m,n] = ctx[m,k] @ wo_t[n,k]^T + bo.
// 128x64 tile, 16 barriers. LDS 24 KB.
// ---------------------------------------------------------------------------
__global__ __launch_bounds__(256) void out_mfma(
    const ushort_t* __restrict__ ctx, const ushort_t* __restrict__ wot,
    const float* __restrict__ bo, float* __restrict__ out)
{
    __shared__ ushort_t As[128 * 64];
    __shared__ ushort_t Bs[64 * 64];

    const int tid  = threadIdx.x;
    const int n0   = blockIdx.x * 64;
    const int m0   = blockIdx.y * 128;
    const int w    = tid >> 6;
    const int lane = tid & 63;
    const int l16  = lane & 15;
    const int quad = lane >> 4;
    const int wm   = (w >> 1) * 64;
    const int wn   = (w & 1) * 32;

    const int srow = tid >> 3;
    const int sc8  = (tid & 7) * 8;
    const ushort_t* aP[4];
#pragma unroll
    for (int j = 0; j < 4; ++j)
        aP[j] = ctx + (size_t)(m0 + srow + j * 32) * C_DIM + sc8;
    const ushort_t* bP[2];
#pragma unroll
    for (int j = 0; j < 2; ++j)
        bP[j] = wot + (size_t)(n0 + srow + j * 32) * C_DIM + sc8;
    const int ldso = tid * 8;

    f32x4 acc[4][2] = {};

    for (int k0 = 0; k0 < C_DIM; k0 += 64) {
        __syncthreads();
#pragma unroll
        for (int j = 0; j < 4; ++j)
            gl_lds16(aP[j] + k0, As + ldso + j * 2048);
#pragma unroll
        for (int j = 0; j < 2; ++j)
            gl_lds16(bP[j] + k0, Bs + ldso + j * 2048);
        __syncthreads();

#pragma unroll
        for (int s = 0; s < 2; ++s) {
            short8 af[4], bf[2];
#pragma unroll
            for (int mi = 0; mi < 4; ++mi)
                af[mi] = *(const short8*)&As[(wm + mi * 16 + l16) * 64 + s * 32 + quad * 8];
#pragma unroll
            for (int ni = 0; ni < 2; ++ni)
                bf[ni] = *(const short8*)&Bs[(wn + ni * 16 + l16) * 64 + s * 32 + quad * 8];
#pragma unroll
            for (int mi = 0; mi < 4; ++mi)
#pragma unroll
                for (int ni = 0; ni < 2; ++ni)
                    acc[mi][ni] = __builtin_amdgcn_mfma_f32_16x16x32_bf16(
                        af[mi], bf[ni], acc[mi][ni], 0, 0, 0);
        }
    }

#pragma unroll
    for (int ni = 0; ni < 2; ++ni) {
        const int n = n0 + wn + ni * 16 + l16;
        const float bias = bo[n];
#pragma unroll
        for (int mi = 0; mi < 4; ++mi) {
            const int mb = m0 + wm + mi * 16 + quad * 4;
#pragma unroll
            for (int r = 0; r < 4; ++r)
                out[(size_t)(mb + r) * C_DIM + n] = acc[mi][ni][r] + bias;
        }
    }
}

extern "C" void kernel_launch(void* const* d_in, const int* in_sizes, int n_in,
                              void* d_out, int out_size, void* d_ws, size_t ws_size,
                              hipStream_t stream)
{
    const float* x  = (const float*)d_in[0];
    const float* wq = (const float*)d_in[1];
    const float* wk = (const float*)d_in[2];
    const float* wv = (const float*)d_in[3];
    const float* wo = (const float*)d_in[4];
    const float* bo = (const float*)d_in[5];
    float* out = (float*)d_out;

    const size_t CC  = (size_t)C_DIM * C_DIM;          // 1.05M
    const size_t MC  = (size_t)M_DIM * C_DIM;          // 4.19M
    ushort_t* xb     = (ushort_t*)d_ws;
    ushort_t* wqkv_t = xb + MC;
    ushort_t* wo_t   = wqkv_t + 3 * CC;
    ushort_t* q_ws   = wo_t + CC;
    ushort_t* k_ws   = q_ws + MC;
    ushort_t* v_t    = k_ws + MC;
    ushort_t* ctx    = v_t + MC;                        // total ~50.3 MB

    hipLaunchKernelGGL(prep, dim3(16, 16, 5), dim3(256), 0, stream,
                       x, wq, wk, wv, wo, xb, wqkv_t, wo_t);
    hipLaunchKernelGGL(qkv_mfma, dim3(24, 32), dim3(256), 0, stream,
                       xb, wqkv_t, q_ws, k_ws, v_t);
    hipLaunchKernelGGL(attn_mfma, dim3(32, 32), dim3(256), 0, stream,
                       q_ws, k_ws, v_t, ctx);
    hipLaunchKernelGGL(out_mfma, dim3(16, 32), dim3(256), 0, stream,
                       ctx, wo_t, bo, out);
}